// Round 1
// baseline (771.517 us; speedup 1.0000x reference)
//
#include <hip/hip_runtime.h>
#include <hip/hip_bf16.h>

// ---------------------------------------------------------------------------
// MCT tracklet-affinity pipeline. fp32 in/out, bf16 MFMA internally.
//   g    = f - relu(f @ Wc1^T + bc1)             [192,4096] fp32 in ws
//   dist = |g_i - g_j| for upper-tri rows        [R,4096] bf16, materialized
//   h1   = relu(dist @ W1^T + b1)                [R,2048] bf16
//   h2   = relu(h1 @ W2^T + b2)                  [R,1024]  (overlays dist)
//   logit[r] += relu(h2 @ W3^T + b3) . Ws        (k_gemm3: fused L3+head dot)
//   A[i,j]=A[j,i]=sigmoid(logit + bs)            (k_sig, once at end)
// Round-10: k_gemm_relu rebuilt as 256x256-tile 8-phase pipelined GEMM
// (m201-class schedule): 512 thr / 8 waves (2Mx4N, 128x64 per wave), BK=64,
// 128 KiB double-buffered LDS, raw s_barrier + counted vmcnt (never 0 in
// steady state), s_setprio(1) around each 16-MFMA cluster. Stage placement
// is provably race-free: B halves of a K-tile are ds_read only in the
// K-tile's first phase, A half h only by wm==h waves; each LDS overwrite is
// issued >=1 barrier after its prior readers' phase completes:
//   p1/p2: A(kt+1) -> buf1-A (readers finished prev iter p8)
//   p3/p4: B(kt+2) -> buf0-B (read only at p1)
//   p5/p6: A(kt+2) -> buf0-A (read p1-p4, done at p4 barrier)
//   p7/p8: B(kt+3) -> buf1-B (read only at p5)
// Boundary waits vmcnt(4) at p4/p8 guarantee the next K-tile resident.
// XOR-swizzled LDS (chunk ^ row&7) carried over from round 7 (0 conflicts).
// k_cam / k_gemm3 keep the proven 128x128 core. Chunk ladder now x256.
// ---------------------------------------------------------------------------

typedef unsigned short u16;
typedef __attribute__((ext_vector_type(8))) short    bf16x8;
typedef __attribute__((ext_vector_type(8))) unsigned short u16x8;
typedef __attribute__((ext_vector_type(4))) float    f32x4;

#define MFMA16(a, b, c) __builtin_amdgcn_mfma_f32_16x16x32_bf16((a), (b), (c), 0, 0, 0)

#define NTRK 192
#define TRI  18528         /* 192*193/2 upper-tri rows incl diagonal */
#define TRIP 18688         /* padded to 73*256 */

__device__ __forceinline__ unsigned int pkbf(float lo, float hi) {
    __hip_bfloat162 h2 = __float22bfloat162_rn(make_float2(lo, hi));
    return *reinterpret_cast<unsigned int*>(&h2);
}
__device__ __forceinline__ void gll16(void* lds_uniform, const void* gsrc) {
    __builtin_amdgcn_global_load_lds(
        (__attribute__((address_space(1))) void*)(gsrc),
        (__attribute__((address_space(3))) void*)(lds_uniform),
        16, 0, 0);
}
// triangle row r -> (i,j), i<=j. T(i) = i*(385-i)/2. Clamped for padding rows.
__device__ __forceinline__ void tri_decode(int r, int& oi, int& oj) {
    double a = 192.5;
    int i = (int)(a - sqrt(a * a - 2.0 * (double)r));
    i = i < 0 ? 0 : (i > 191 ? 191 : i);
    while (i < 191 && (i + 1) * (385 - (i + 1)) / 2 <= r) ++i;
    while (i > 0 && i * (385 - i) / 2 > r) --i;
    int j = i + (r - i * (385 - i) / 2);
    oi = i; oj = j > 191 ? 191 : j;
}

// ---------------------------------------------------------------------------
// All five fp32->bf16 conversions in ONE launch. Segment sizes in f32x4:
// Wc1 4194304 | W1 2097152 | W2 524288 | W3 131072 | f 196608  (sum 7143424)
// ---------------------------------------------------------------------------
#define CVT_N 7143424
__global__ __launch_bounds__(256)
void k_cvt_all(const float* __restrict__ s0, u16* __restrict__ d0,
               const float* __restrict__ s1, u16* __restrict__ d1,
               const float* __restrict__ s2, u16* __restrict__ d2,
               const float* __restrict__ s3, u16* __restrict__ d3,
               const float* __restrict__ s4, u16* __restrict__ d4)
{
    int i = blockIdx.x * 256 + threadIdx.x;
    if (i >= CVT_N) return;
    const float* s; u16* d; int j;
    if      (i < 4194304) { s = s0; d = d0; j = i; }
    else if (i < 6291456) { s = s1; d = d1; j = i - 4194304; }
    else if (i < 6815744) { s = s2; d = d2; j = i - 6291456; }
    else if (i < 6946816) { s = s3; d = d3; j = i - 6815744; }
    else                  { s = s4; d = d4; j = i - 6946816; }
    f32x4 v = ((const f32x4*)s)[j];
    ((uint2*)d)[j] = make_uint2(pkbf(v.x, v.y), pkbf(v.z, v.w));
}

// ---------------------------------------------------------------------------
// cam partials: camp[z][row][col] = (fb @ Wc1b^T) over k in [z*1024,(z+1)*1024)
// M=192,N=4096. BM=64,BN=128,BK=64, split-K=4 via blockIdx.z. grid (3,32,4).
// ---------------------------------------------------------------------------
__global__ __launch_bounds__(256, 2)
void k_cam(const u16* __restrict__ fb, const u16* __restrict__ Wc1b,
           float* __restrict__ camp)
{
    __shared__ __align__(16) u16 As[64 * 64];
    __shared__ __align__(16) u16 Bs[128 * 64];
    const int t = threadIdx.x, l = t & 63, w = t >> 6;
    const int m0 = blockIdx.x * 64, n0 = blockIdx.y * 128;
    const int kbeg = blockIdx.z * 1024, kend = kbeg + 1024;
    const int lr8 = l >> 3;
    const int lc8 = (l & 7) ^ lr8;
    const u16* Ab = fb   + (size_t)(m0 + w * 16 + lr8) * 4096 + lc8 * 8;
    const u16* Bb = Wc1b + (size_t)(n0 + w * 32 + lr8) * 4096 + lc8 * 8;
    f32x4 acc[2][4] = {};
    const int wr = (w >> 1) * 32, wc = (w & 1) * 64;
    const int lrow = l & 15, lq = l >> 4, s = lrow & 7;

    for (int k0 = kbeg; k0 < kend; k0 += 64) {
        __syncthreads();
#pragma unroll
        for (int q = 0; q < 2; ++q)
            gll16(&As[(w * 16 + q * 8) * 64], Ab + (size_t)q * 8 * 4096 + k0);
#pragma unroll
        for (int q = 0; q < 4; ++q)
            gll16(&Bs[(w * 32 + q * 8) * 64], Bb + (size_t)q * 8 * 4096 + k0);
        __syncthreads();
#pragma unroll
        for (int kk8 = 0; kk8 < 8; kk8 += 4) {
            const int co = ((kk8 + lq) ^ s) * 8;
            bf16x8 af[2], bfr[4];
#pragma unroll
            for (int mi = 0; mi < 2; ++mi)
                af[mi] = *(const bf16x8*)&As[(wr + mi * 16 + lrow) * 64 + co];
#pragma unroll
            for (int ni = 0; ni < 4; ++ni)
                bfr[ni] = *(const bf16x8*)&Bs[(wc + ni * 16 + lrow) * 64 + co];
#pragma unroll
            for (int mi = 0; mi < 2; ++mi)
#pragma unroll
                for (int ni = 0; ni < 4; ++ni)
                    acc[mi][ni] = MFMA16(af[mi], bfr[ni], acc[mi][ni]);
        }
    }
    float* cz = camp + (size_t)blockIdx.z * 192 * 4096;
    const int rq = (l >> 4) * 4;
#pragma unroll
    for (int ni = 0; ni < 4; ++ni) {
        const int col = n0 + wc + ni * 16 + lrow;
#pragma unroll
        for (int mi = 0; mi < 2; ++mi) {
            const int rbase = m0 + wr + mi * 16 + rq;
#pragma unroll
            for (int v = 0; v < 4; ++v)
                cz[(size_t)(rbase + v) * 4096 + col] = acc[mi][ni][v];
        }
    }
}

// ---------------------------------------------------------------------------
// g = f - relu(sum_z camp[z] + bc1). 196608 f32x4 groups, grid 768.
// ---------------------------------------------------------------------------
__global__ __launch_bounds__(256)
void k_gfin(const float* __restrict__ camp, const float* __restrict__ bc1,
            const float* __restrict__ f, float* __restrict__ g)
{
    const int i = blockIdx.x * 256 + threadIdx.x;       // < 196608
    const int col4 = (i * 4) & 4095;
    f32x4 p0 = ((const f32x4*)camp)[i];
    f32x4 p1 = ((const f32x4*)(camp + 786432))[i];
    f32x4 p2 = ((const f32x4*)(camp + 1572864))[i];
    f32x4 p3 = ((const f32x4*)(camp + 2359296))[i];
    f32x4 b = *(const f32x4*)(bc1 + col4);
    f32x4 fv = ((const f32x4*)f)[i];
    f32x4 r;
    r.x = fv.x - fmaxf(p0.x + p1.x + p2.x + p3.x + b.x, 0.0f);
    r.y = fv.y - fmaxf(p0.y + p1.y + p2.y + p3.y + b.y, 0.0f);
    r.z = fv.z - fmaxf(p0.z + p1.z + p2.z + p3.z + b.z, 0.0f);
    r.w = fv.w - fmaxf(p0.w + p1.w + p2.w + p3.w + b.w, 0.0f);
    ((f32x4*)g)[i] = r;
}

// ---------------------------------------------------------------------------
// dist[r, :] = bf16(|g_i - g_j|). One 16B chunk per thread. grid (2, rows).
// ---------------------------------------------------------------------------
__global__ __launch_bounds__(256)
void k_distgen(const float* __restrict__ g, u16* __restrict__ dist, int row0)
{
    const int r = blockIdx.y;
    const int c = blockIdx.x * 256 + threadIdx.x;       // chunk 0..511
    int pi, pj; tri_decode(row0 + r, pi, pj);
    const float* gi = g + (size_t)pi * 4096 + c * 8;
    const float* gj = g + (size_t)pj * 4096 + c * 8;
    f32x4 a0 = ((const f32x4*)gi)[0], a1 = ((const f32x4*)gi)[1];
    f32x4 b0 = ((const f32x4*)gj)[0], b1 = ((const f32x4*)gj)[1];
    uint4 o;
    o.x = pkbf(fabsf(b0.x - a0.x), fabsf(b0.y - a0.y));
    o.y = pkbf(fabsf(b0.z - a0.z), fabsf(b0.w - a0.w));
    o.z = pkbf(fabsf(b1.x - a1.x), fabsf(b1.y - a1.y));
    o.w = pkbf(fabsf(b1.z - a1.z), fabsf(b1.w - a1.w));
    *reinterpret_cast<uint4*>(dist + (size_t)r * 4096 + c * 8) = o;
}

// ---------------------------------------------------------------------------
// C = relu(A @ B^T + bias), bf16. 256x256 tile, BK=64, 512 thr / 8 waves,
// 8-phase pipelined schedule (see header comment). M, N multiples of 256.
// Per wave: 128x64 output = acc[8][4] f32x4. grid (N/256, M/256), x = col.
// ---------------------------------------------------------------------------
__global__ __launch_bounds__(512, 2)
void k_gemm_relu(const u16* __restrict__ A, const u16* __restrict__ B,
                 const float* __restrict__ bias, u16* __restrict__ C,
                 int N, int K)
{
    __shared__ __align__(16) u16 As[2][256 * 64];   // 64 KiB
    __shared__ __align__(16) u16 Bs[2][256 * 64];   // 64 KiB
    const int t = threadIdx.x, l = t & 63, w = t >> 6;
    const int m0 = blockIdx.y * 256, n0 = blockIdx.x * 256;   // x = column!
    const int lr8 = l >> 3;
    const int lc8 = (l & 7) ^ lr8;          // pre-swizzled source chunk
    const int wm = w >> 2, wn = w & 3;      // wave tile: rows wm*128, cols wn*64
    const int lrow = l & 15, lq = l >> 4, s = lrow & 7;

    const u16* Ab = A + (size_t)(m0 + w * 8 + lr8) * K + lc8 * 8;
    const u16* Bb = B + (size_t)(n0 + w * 8 + lr8) * K + lc8 * 8;
    const size_t row64 = (size_t)64 * K;

    f32x4 acc[8][4] = {};
    const int NIT = K >> 7;                 // 2 K-tiles (of 64) per iteration

// stage half-tile (128 rows) ha of A / hb of B for K-tile kt_ (2 x gll16)
#define SA(kt_, ha_) do { \
    u16* lb_ = &As[(kt_) & 1][((ha_) * 128 + w * 8) * 64]; \
    const u16* gs_ = Ab + (size_t)(ha_) * 128 * K + (kt_) * 64; \
    gll16(lb_, gs_); gll16(lb_ + 64 * 64, gs_ + row64); \
} while (0)
#define SB(kt_, hb_) do { \
    u16* lb_ = &Bs[(kt_) & 1][((hb_) * 128 + w * 8) * 64]; \
    const u16* gs_ = Bb + (size_t)(hb_) * 128 * K + (kt_) * 64; \
    gll16(lb_, gs_); gll16(lb_ + 64 * 64, gs_ + row64); \
} while (0)

// one phase: ds-read A quadrant (+B on first phase of K-tile), issue stage,
// barrier, MFMA cluster under setprio, boundary wait, barrier.
#define PHASE(p_, q_, RDB_, STG_, WAIT_) do { \
    bf16x8 af[2][2]; \
    _Pragma("unroll") \
    for (int kk = 0; kk < 2; ++kk) { \
        _Pragma("unroll") \
        for (int mi = 0; mi < 2; ++mi) \
            af[kk][mi] = *(const bf16x8*)&As[p_][(wm * 128 + (q_) * 32 + mi * 16 + lrow) * 64 + ((kk * 4 + lq) ^ s) * 8]; \
        if (RDB_) { \
            _Pragma("unroll") \
            for (int ni = 0; ni < 4; ++ni) \
                bf[kk][ni] = *(const bf16x8*)&Bs[p_][(wn * 64 + ni * 16 + lrow) * 64 + ((kk * 4 + lq) ^ s) * 8]; \
        } \
    } \
    STG_ \
    __builtin_amdgcn_s_barrier(); \
    asm volatile("s_waitcnt lgkmcnt(0)" ::: "memory"); \
    __builtin_amdgcn_s_setprio(1); \
    _Pragma("unroll") \
    for (int kk = 0; kk < 2; ++kk) \
        _Pragma("unroll") \
        for (int mi = 0; mi < 2; ++mi) \
            _Pragma("unroll") \
            for (int ni = 0; ni < 4; ++ni) \
                acc[(q_) * 2 + mi][ni] = MFMA16(af[kk][mi], bf[kk][ni], acc[(q_) * 2 + mi][ni]); \
    __builtin_amdgcn_s_setprio(0); \
    WAIT_ \
    __builtin_amdgcn_s_barrier(); \
} while (0)

    // prologue: kt0 fully + B of kt1. 12 loads; wait until kt0 (8) landed.
    SA(0, 0); SA(0, 1); SB(0, 0); SB(0, 1);
    SB(1, 0); SB(1, 1);
    asm volatile("s_waitcnt vmcnt(4)" ::: "memory");
    __builtin_amdgcn_s_barrier();

    for (int it = 0; it < NIT; ++it) {
        const int kt = 2 * it;
        const bool hn = (it + 1 < NIT);
        bf16x8 bf[2][4];
        // phases 1-4: K-tile kt (buf 0)
        PHASE(0, 0, 1, SA(kt + 1, 0);, );
        PHASE(0, 1, 0, SA(kt + 1, 1);, );
        PHASE(0, 2, 0, if (hn) SB(kt + 2, 0);, );
        PHASE(0, 3, 0, if (hn) SB(kt + 2, 1);,
              if (hn) { asm volatile("s_waitcnt vmcnt(4)" ::: "memory"); }
              else    { asm volatile("s_waitcnt vmcnt(0)" ::: "memory"); } );
        // phases 5-8: K-tile kt+1 (buf 1)
        PHASE(1, 0, 1, if (hn) SA(kt + 2, 0);, );
        PHASE(1, 1, 0, if (hn) SA(kt + 2, 1);, );
        PHASE(1, 2, 0, if (hn) SB(kt + 3, 0);, );
        PHASE(1, 3, 0, if (hn) SB(kt + 3, 1);,
              if (hn) { asm volatile("s_waitcnt vmcnt(4)" ::: "memory"); } );
    }
#undef SA
#undef SB
#undef PHASE

    const int rq = lq * 4;
#pragma unroll
    for (int ni = 0; ni < 4; ++ni) {
        const int col = n0 + wn * 64 + ni * 16 + lrow;
        const float bv = bias[col];
#pragma unroll
        for (int mi = 0; mi < 8; ++mi) {
            const int rbase = m0 + wm * 128 + mi * 16 + rq;
#pragma unroll
            for (int v = 0; v < 4; ++v) {
                float x = fmaxf(acc[mi][ni][v] + bv, 0.0f);
                C[(size_t)(rbase + v) * N + col] = (u16)(pkbf(x, 0.0f) & 0xFFFF);
            }
        }
    }
}

// ---------------------------------------------------------------------------
// Fused L3+head: logit[r0+row] += sum_col relu(h2@W3^T + b3)[row,col]*Ws[col].
// 128x128 core (N=512, K=1024, grid (4, rows/128)). Epilogue: per (mi,v)
// row-slot, dot partial over this lane's 4 cols, butterfly-reduce across the
// 16 lrow lanes, one fp32 atomicAdd per row-slot from lane lrow==0.
// ---------------------------------------------------------------------------
__global__ __launch_bounds__(256, 2)
void k_gemm3(const u16* __restrict__ A, const u16* __restrict__ B,
             const float* __restrict__ bias, const float* __restrict__ Wsv,
             float* __restrict__ logit, int r0)
{
    const int N = 512, K = 1024;
    __shared__ __align__(16) u16 As[128 * 64];
    __shared__ __align__(16) u16 Bs[128 * 64];
    const int t = threadIdx.x, l = t & 63, w = t >> 6;
    const int m0 = blockIdx.y * 128, n0 = blockIdx.x * 128;
    const int lr8 = l >> 3;
    const int lc8 = (l & 7) ^ lr8;
    const u16* Ab = A + (size_t)(m0 + w * 32 + lr8) * K + lc8 * 8;
    const u16* Bb = B + (size_t)(n0 + w * 32 + lr8) * K + lc8 * 8;
    f32x4 acc[4][4] = {};
    const int wr = (w >> 1) * 64, wc = (w & 1) * 64;
    const int lrow = l & 15, lq = l >> 4, s = lrow & 7;

    for (int k0 = 0; k0 < K; k0 += 64) {
        __syncthreads();
#pragma unroll
        for (int q = 0; q < 4; ++q) {
            gll16(&As[(w * 32 + q * 8) * 64], Ab + (size_t)q * 8 * K + k0);
            gll16(&Bs[(w * 32 + q * 8) * 64], Bb + (size_t)q * 8 * K + k0);
        }
        __syncthreads();
#pragma unroll
        for (int kk8 = 0; kk8 < 8; kk8 += 4) {
            const int co = ((kk8 + lq) ^ s) * 8;
            bf16x8 af[4], bfr[4];
#pragma unroll
            for (int mi = 0; mi < 4; ++mi)
                af[mi] = *(const bf16x8*)&As[(wr + mi * 16 + lrow) * 64 + co];
#pragma unroll
            for (int ni = 0; ni < 4; ++ni)
                bfr[ni] = *(const bf16x8*)&Bs[(wc + ni * 16 + lrow) * 64 + co];
#pragma unroll
            for (int mi = 0; mi < 4; ++mi)
#pragma unroll
                for (int ni = 0; ni < 4; ++ni)
                    acc[mi][ni] = MFMA16(af[mi], bfr[ni], acc[mi][ni]);
        }
    }
    const int rq = (l >> 4) * 4;
    float wv[4], bv[4];
#pragma unroll
    for (int ni = 0; ni < 4; ++ni) {
        const int col = n0 + wc + ni * 16 + lrow;
        wv[ni] = Wsv[col];
        bv[ni] = bias[col];
    }
#pragma unroll
    for (int mi = 0; mi < 4; ++mi) {
#pragma unroll
        for (int v = 0; v < 4; ++v) {
            float p = 0.0f;
#pragma unroll
            for (int ni = 0; ni < 4; ++ni)
                p += fmaxf(acc[mi][ni][v] + bv[ni], 0.0f) * wv[ni];
            p += __shfl_xor(p, 1, 64);
            p += __shfl_xor(p, 2, 64);
            p += __shfl_xor(p, 4, 64);
            p += __shfl_xor(p, 8, 64);
            if (lrow == 0)
                atomicAdd(&logit[r0 + m0 + wr + mi * 16 + rq + v], p);
        }
    }
}

// ---------------------------------------------------------------------------
// out[i,j] = out[j,i] = sigmoid(logit[r] + bs). One thread per tri-row.
// ---------------------------------------------------------------------------
__global__ __launch_bounds__(256)
void k_sig(const float* __restrict__ logit, const float* __restrict__ bsv,
           float* __restrict__ out)
{
    const int r = blockIdx.x * 256 + threadIdx.x;
    if (r >= TRI) return;
    int pi, pj; tri_decode(r, pi, pj);
    float v = 1.0f / (1.0f + __expf(-(logit[r] + bsv[0])));
    out[pi * NTRK + pj] = v;
    out[pj * NTRK + pi] = v;
}

// ---------------------------------------------------------------------------
extern "C" void kernel_launch(void* const* d_in, const int* in_sizes, int n_in,
                              void* d_out, int out_size, void* d_ws, size_t ws_size,
                              hipStream_t stream)
{
    const float* f   = (const float*)d_in[0];
    const float* Wc1 = (const float*)d_in[1];
    const float* bc1 = (const float*)d_in[2];
    const float* W1  = (const float*)d_in[3];
    const float* b1  = (const float*)d_in[4];
    const float* W2  = (const float*)d_in[5];
    const float* b2  = (const float*)d_in[6];
    const float* W3  = (const float*)d_in[7];
    const float* b3  = (const float*)d_in[8];
    const float* Wsv = (const float*)d_in[9];
    const float* bsv = (const float*)d_in[10];
    float* out = (float*)d_out;

    // ---- workspace layout ----
    // persistent: W1b 16M | W2b 4M | W3b 1M | fb 1.5M | g 3M | logit 75K
    // overlay region at chunkbase:
    //   phase A: Wc1b (32M) + camp (12M)   [dead before chunk loop]
    //   phase B: dist (8192R) + h1 (4096R); h2 (2048R) overlays dist.
    char* wsb = (char*)d_ws;
    size_t off = 0;
    u16*   W1b   = (u16*)(wsb + off);  off += (size_t)2048 * 4096 * 2;
    u16*   W2b   = (u16*)(wsb + off);  off += (size_t)1024 * 2048 * 2;
    u16*   W3b   = (u16*)(wsb + off);  off += (size_t)512  * 1024 * 2;
    u16*   fb    = (u16*)(wsb + off);  off += (size_t)192  * 4096 * 2;
    float* g     = (float*)(wsb + off); off += (size_t)192 * 4096 * 4;
    float* logit = (float*)(wsb + off); off += (size_t)TRIP * 4;
    const size_t chunkbase = off;
    u16*   Wc1b = (u16*)(wsb + chunkbase);
    float* camp = (float*)(wsb + chunkbase + (size_t)4096 * 4096 * 2);
    const size_t phaseA = (size_t)4096 * 4096 * 2 + (size_t)4 * 192 * 4096 * 4;

    // chunk rows must be multiples of 256 (256-row GEMM tiles)
    const int Rcand[6] = {18688, 14336, 9472, 4864, 2560, 1280};
    int R = 256;
    for (int c = 0; c < 6; ++c) {
        size_t chunk = (size_t)Rcand[c] * 12288;
        if (chunk < phaseA) chunk = phaseA;
        if (chunkbase + chunk <= ws_size) { R = Rcand[c]; break; }
    }
    u16* dist = (u16*)(wsb + chunkbase);
    u16* h1 = dist + (size_t)R * 4096;
    u16* h2 = dist;                       // overlays dist (dead after L1)

    hipMemsetAsync(logit, 0, (size_t)TRIP * 4, stream);
    k_cvt_all<<<(CVT_N + 255) / 256, 256, 0, stream>>>(
        Wc1, Wc1b, W1, W1b, W2, W2b, W3, W3b, f, fb);
    k_cam<<<dim3(3, 32, 4), 256, 0, stream>>>(fb, Wc1b, camp);
    k_gfin<<<768, 256, 0, stream>>>(camp, bc1, f, g);

    for (int r0 = 0; r0 < TRI; r0 += R) {
        int rows = TRIP - r0; if (rows > R) rows = R;   // mult of 256
        k_distgen<<<dim3(2, rows), 256, 0, stream>>>(g, dist, r0);
        k_gemm_relu<<<dim3(8, rows / 256), 512, 0, stream>>>(dist, W1b, b1, h1, 2048, 4096);
        k_gemm_relu<<<dim3(4, rows / 256), 512, 0, stream>>>(h1, W2b, b2, h2, 1024, 2048);
        k_gemm3<<<dim3(4, rows / 128), 256, 0, stream>>>(h2, W3b, b3, Wsv, logit, r0);
    }
    k_sig<<<(TRI + 255) / 256, 256, 0, stream>>>(logit, bsv, out);
}

// Round 2
// 644.717 us; speedup vs baseline: 1.1967x; 1.1967x over previous
//
#include <hip/hip_runtime.h>
#include <hip/hip_bf16.h>

// ---------------------------------------------------------------------------
// MCT tracklet-affinity pipeline. fp32 in/out, bf16 MFMA internally.
//   g    = f - relu(f @ Wc1^T + bc1)             [192,4096] fp32 in ws
//   dist = |g_i - g_j| for upper-tri rows        [R,4096] bf16, materialized
//   h1   = relu(dist @ W1^T + b1)                [R,2048] bf16
//   h2   = relu(h1 @ W2^T + b2)                  [R,1024]  (overlays dist)
//   logit[r] += relu(h2 @ W3^T + b3) . Ws        (k_gemm3: fused L3+head dot,
//                                                 fp32 atomicAdd per row)
//   A[i,j]=A[j,i]=sigmoid(logit + bs)            (k_sig, once at end)
// Round-11: REVERT to the proven round-9 128x128 2-barrier GEMM core
// (round-10's 256^2 8-phase port collapsed to ~589 TF/resident: 32% MfmaUtil,
// 18% occupancy — the m232 "derived-waits" failure mode; do not retry without
// the exact m201 wait schedule). Single change vs round-9: chunk ladder picks
// R=12288 so the big L1 dispatch is 1536 blocks = 6.0/CU = 3x512 = 2x768 —
// tail-free under per-CU AND residency scheduling models (was 1792/544).
// GEMM core: 16x16x32 MFMA, XOR-swizzled LDS (0 bank conflicts),
// x = column tile for XCD L2 locality, global_load_lds width-16 staging.
// ---------------------------------------------------------------------------

typedef unsigned short u16;
typedef __attribute__((ext_vector_type(8))) short    bf16x8;
typedef __attribute__((ext_vector_type(8))) unsigned short u16x8;
typedef __attribute__((ext_vector_type(4))) float    f32x4;

#define MFMA16(a, b, c) __builtin_amdgcn_mfma_f32_16x16x32_bf16((a), (b), (c), 0, 0, 0)

#define NTRK 192
#define TRI  18528         /* 192*193/2 upper-tri rows incl diagonal */
#define TRIP 18688         /* padded to 146*128 */

__device__ __forceinline__ unsigned int pkbf(float lo, float hi) {
    __hip_bfloat162 h2 = __float22bfloat162_rn(make_float2(lo, hi));
    return *reinterpret_cast<unsigned int*>(&h2);
}
__device__ __forceinline__ void gll16(void* lds_uniform, const void* gsrc) {
    __builtin_amdgcn_global_load_lds(
        (__attribute__((address_space(1))) void*)(gsrc),
        (__attribute__((address_space(3))) void*)(lds_uniform),
        16, 0, 0);
}
// triangle row r -> (i,j), i<=j. T(i) = i*(385-i)/2. Clamped for padding rows.
__device__ __forceinline__ void tri_decode(int r, int& oi, int& oj) {
    double a = 192.5;
    int i = (int)(a - sqrt(a * a - 2.0 * (double)r));
    i = i < 0 ? 0 : (i > 191 ? 191 : i);
    while (i < 191 && (i + 1) * (385 - (i + 1)) / 2 <= r) ++i;
    while (i > 0 && i * (385 - i) / 2 > r) --i;
    int j = i + (r - i * (385 - i) / 2);
    oi = i; oj = j > 191 ? 191 : j;
}

// ---------------------------------------------------------------------------
// All five fp32->bf16 conversions in ONE launch. Segment sizes in f32x4:
// Wc1 4194304 | W1 2097152 | W2 524288 | W3 131072 | f 196608  (sum 7143424)
// ---------------------------------------------------------------------------
#define CVT_N 7143424
__global__ __launch_bounds__(256)
void k_cvt_all(const float* __restrict__ s0, u16* __restrict__ d0,
               const float* __restrict__ s1, u16* __restrict__ d1,
               const float* __restrict__ s2, u16* __restrict__ d2,
               const float* __restrict__ s3, u16* __restrict__ d3,
               const float* __restrict__ s4, u16* __restrict__ d4)
{
    int i = blockIdx.x * 256 + threadIdx.x;
    if (i >= CVT_N) return;
    const float* s; u16* d; int j;
    if      (i < 4194304) { s = s0; d = d0; j = i; }
    else if (i < 6291456) { s = s1; d = d1; j = i - 4194304; }
    else if (i < 6815744) { s = s2; d = d2; j = i - 6291456; }
    else if (i < 6946816) { s = s3; d = d3; j = i - 6815744; }
    else                  { s = s4; d = d4; j = i - 6946816; }
    f32x4 v = ((const f32x4*)s)[j];
    ((uint2*)d)[j] = make_uint2(pkbf(v.x, v.y), pkbf(v.z, v.w));
}

// ---------------------------------------------------------------------------
// cam partials: camp[z][row][col] = (fb @ Wc1b^T) over k in [z*1024,(z+1)*1024)
// M=192,N=4096. BM=64,BN=128,BK=64, split-K=4 via blockIdx.z. grid (3,32,4).
// ---------------------------------------------------------------------------
__global__ __launch_bounds__(256, 2)
void k_cam(const u16* __restrict__ fb, const u16* __restrict__ Wc1b,
           float* __restrict__ camp)
{
    __shared__ __align__(16) u16 As[64 * 64];
    __shared__ __align__(16) u16 Bs[128 * 64];
    const int t = threadIdx.x, l = t & 63, w = t >> 6;
    const int m0 = blockIdx.x * 64, n0 = blockIdx.y * 128;
    const int kbeg = blockIdx.z * 1024, kend = kbeg + 1024;
    const int lr8 = l >> 3;
    const int lc8 = (l & 7) ^ lr8;
    const u16* Ab = fb   + (size_t)(m0 + w * 16 + lr8) * 4096 + lc8 * 8;
    const u16* Bb = Wc1b + (size_t)(n0 + w * 32 + lr8) * 4096 + lc8 * 8;
    f32x4 acc[2][4] = {};
    const int wr = (w >> 1) * 32, wc = (w & 1) * 64;
    const int lrow = l & 15, lq = l >> 4, s = lrow & 7;

    for (int k0 = kbeg; k0 < kend; k0 += 64) {
        __syncthreads();
#pragma unroll
        for (int q = 0; q < 2; ++q)
            gll16(&As[(w * 16 + q * 8) * 64], Ab + (size_t)q * 8 * 4096 + k0);
#pragma unroll
        for (int q = 0; q < 4; ++q)
            gll16(&Bs[(w * 32 + q * 8) * 64], Bb + (size_t)q * 8 * 4096 + k0);
        __syncthreads();
#pragma unroll
        for (int kk8 = 0; kk8 < 8; kk8 += 4) {
            const int co = ((kk8 + lq) ^ s) * 8;
            bf16x8 af[2], bfr[4];
#pragma unroll
            for (int mi = 0; mi < 2; ++mi)
                af[mi] = *(const bf16x8*)&As[(wr + mi * 16 + lrow) * 64 + co];
#pragma unroll
            for (int ni = 0; ni < 4; ++ni)
                bfr[ni] = *(const bf16x8*)&Bs[(wc + ni * 16 + lrow) * 64 + co];
#pragma unroll
            for (int mi = 0; mi < 2; ++mi)
#pragma unroll
                for (int ni = 0; ni < 4; ++ni)
                    acc[mi][ni] = MFMA16(af[mi], bfr[ni], acc[mi][ni]);
        }
    }
    float* cz = camp + (size_t)blockIdx.z * 192 * 4096;
    const int rq = (l >> 4) * 4;
#pragma unroll
    for (int ni = 0; ni < 4; ++ni) {
        const int col = n0 + wc + ni * 16 + lrow;
#pragma unroll
        for (int mi = 0; mi < 2; ++mi) {
            const int rbase = m0 + wr + mi * 16 + rq;
#pragma unroll
            for (int v = 0; v < 4; ++v)
                cz[(size_t)(rbase + v) * 4096 + col] = acc[mi][ni][v];
        }
    }
}

// ---------------------------------------------------------------------------
// g = f - relu(sum_z camp[z] + bc1). 196608 f32x4 groups, grid 768.
// ---------------------------------------------------------------------------
__global__ __launch_bounds__(256)
void k_gfin(const float* __restrict__ camp, const float* __restrict__ bc1,
            const float* __restrict__ f, float* __restrict__ g)
{
    const int i = blockIdx.x * 256 + threadIdx.x;       // < 196608
    const int col4 = (i * 4) & 4095;
    f32x4 p0 = ((const f32x4*)camp)[i];
    f32x4 p1 = ((const f32x4*)(camp + 786432))[i];
    f32x4 p2 = ((const f32x4*)(camp + 1572864))[i];
    f32x4 p3 = ((const f32x4*)(camp + 2359296))[i];
    f32x4 b = *(const f32x4*)(bc1 + col4);
    f32x4 fv = ((const f32x4*)f)[i];
    f32x4 r;
    r.x = fv.x - fmaxf(p0.x + p1.x + p2.x + p3.x + b.x, 0.0f);
    r.y = fv.y - fmaxf(p0.y + p1.y + p2.y + p3.y + b.y, 0.0f);
    r.z = fv.z - fmaxf(p0.z + p1.z + p2.z + p3.z + b.z, 0.0f);
    r.w = fv.w - fmaxf(p0.w + p1.w + p2.w + p3.w + b.w, 0.0f);
    ((f32x4*)g)[i] = r;
}

// ---------------------------------------------------------------------------
// dist[r, :] = bf16(|g_i - g_j|). One 16B chunk per thread. grid (2, rows).
// ---------------------------------------------------------------------------
__global__ __launch_bounds__(256)
void k_distgen(const float* __restrict__ g, u16* __restrict__ dist, int row0)
{
    const int r = blockIdx.y;
    const int c = blockIdx.x * 256 + threadIdx.x;       // chunk 0..511
    int pi, pj; tri_decode(row0 + r, pi, pj);
    const float* gi = g + (size_t)pi * 4096 + c * 8;
    const float* gj = g + (size_t)pj * 4096 + c * 8;
    f32x4 a0 = ((const f32x4*)gi)[0], a1 = ((const f32x4*)gi)[1];
    f32x4 b0 = ((const f32x4*)gj)[0], b1 = ((const f32x4*)gj)[1];
    uint4 o;
    o.x = pkbf(fabsf(b0.x - a0.x), fabsf(b0.y - a0.y));
    o.y = pkbf(fabsf(b0.z - a0.z), fabsf(b0.w - a0.w));
    o.z = pkbf(fabsf(b1.x - a1.x), fabsf(b1.y - a1.y));
    o.w = pkbf(fabsf(b1.z - a1.z), fabsf(b1.w - a1.w));
    *reinterpret_cast<uint4*>(dist + (size_t)r * 4096 + c * 8) = o;
}

// ---------------------------------------------------------------------------
// C = relu(A @ B^T + bias), bf16, 16x16x32 MFMA. BM=BN=128, BK=64, 256 thr,
// wave tile 64x64. grid (N/128, M/128): x = COLUMN tile (fast).
// XOR-swizzled LDS: stage chunk (l&7)^(l>>3), read chunk (ck)^(row&7).
// ---------------------------------------------------------------------------
__global__ __launch_bounds__(256, 2)
void k_gemm_relu(const u16* __restrict__ A, const u16* __restrict__ B,
                 const float* __restrict__ bias, u16* __restrict__ C,
                 int N, int K)
{
    __shared__ __align__(16) u16 As[128 * 64];
    __shared__ __align__(16) u16 Bs[128 * 64];
    const int t = threadIdx.x, l = t & 63, w = t >> 6;
    const int m0 = blockIdx.y * 128, n0 = blockIdx.x * 128;   // x = column!
    const int lr8 = l >> 3;
    const int lc8 = (l & 7) ^ lr8;
    const u16* Ab = A + (size_t)(m0 + w * 32 + lr8) * K + lc8 * 8;
    const u16* Bb = B + (size_t)(n0 + w * 32 + lr8) * K + lc8 * 8;
    f32x4 acc[4][4] = {};
    const int wr = (w >> 1) * 64, wc = (w & 1) * 64;
    const int lrow = l & 15, lq = l >> 4, s = lrow & 7;

    for (int k0 = 0; k0 < K; k0 += 64) {
        __syncthreads();
#pragma unroll
        for (int q = 0; q < 4; ++q) {
            gll16(&As[(w * 32 + q * 8) * 64], Ab + (size_t)q * 8 * K + k0);
            gll16(&Bs[(w * 32 + q * 8) * 64], Bb + (size_t)q * 8 * K + k0);
        }
        __syncthreads();
#pragma unroll
        for (int kk8 = 0; kk8 < 8; kk8 += 4) {
            const int co = ((kk8 + lq) ^ s) * 8;
            bf16x8 af[4], bfr[4];
#pragma unroll
            for (int mi = 0; mi < 4; ++mi)
                af[mi] = *(const bf16x8*)&As[(wr + mi * 16 + lrow) * 64 + co];
#pragma unroll
            for (int ni = 0; ni < 4; ++ni)
                bfr[ni] = *(const bf16x8*)&Bs[(wc + ni * 16 + lrow) * 64 + co];
#pragma unroll
            for (int mi = 0; mi < 4; ++mi)
#pragma unroll
                for (int ni = 0; ni < 4; ++ni)
                    acc[mi][ni] = MFMA16(af[mi], bfr[ni], acc[mi][ni]);
        }
    }
    const int rq = (l >> 4) * 4;
#pragma unroll
    for (int ni = 0; ni < 4; ++ni) {
        const int col = n0 + wc + ni * 16 + lrow;
        const float bv = bias[col];
#pragma unroll
        for (int mi = 0; mi < 4; ++mi) {
            const int rbase = m0 + wr + mi * 16 + rq;
#pragma unroll
            for (int v = 0; v < 4; ++v) {
                float x = fmaxf(acc[mi][ni][v] + bv, 0.0f);
                C[(size_t)(rbase + v) * N + col] = (u16)(pkbf(x, 0.0f) & 0xFFFF);
            }
        }
    }
}

// ---------------------------------------------------------------------------
// Fused L3+head: logit[r0+row] += sum_col relu(h2@W3^T + b3)[row,col]*Ws[col].
// Same GEMM core (N=512, K=1024, grid (4, rows/128)). Epilogue: per (mi,v)
// row-slot, dot partial over this lane's 4 cols, butterfly-reduce across the
// 16 lrow lanes (xor masks 1,2,4,8 stay within the l>>4 quad since row is
// determined by l>>4), one fp32 atomicAdd per row-slot from lane lrow==0.
// ---------------------------------------------------------------------------
__global__ __launch_bounds__(256, 2)
void k_gemm3(const u16* __restrict__ A, const u16* __restrict__ B,
             const float* __restrict__ bias, const float* __restrict__ Wsv,
             float* __restrict__ logit, int r0)
{
    const int N = 512, K = 1024;
    __shared__ __align__(16) u16 As[128 * 64];
    __shared__ __align__(16) u16 Bs[128 * 64];
    const int t = threadIdx.x, l = t & 63, w = t >> 6;
    const int m0 = blockIdx.y * 128, n0 = blockIdx.x * 128;
    const int lr8 = l >> 3;
    const int lc8 = (l & 7) ^ lr8;
    const u16* Ab = A + (size_t)(m0 + w * 32 + lr8) * K + lc8 * 8;
    const u16* Bb = B + (size_t)(n0 + w * 32 + lr8) * K + lc8 * 8;
    f32x4 acc[4][4] = {};
    const int wr = (w >> 1) * 64, wc = (w & 1) * 64;
    const int lrow = l & 15, lq = l >> 4, s = lrow & 7;

    for (int k0 = 0; k0 < K; k0 += 64) {
        __syncthreads();
#pragma unroll
        for (int q = 0; q < 4; ++q) {
            gll16(&As[(w * 32 + q * 8) * 64], Ab + (size_t)q * 8 * K + k0);
            gll16(&Bs[(w * 32 + q * 8) * 64], Bb + (size_t)q * 8 * K + k0);
        }
        __syncthreads();
#pragma unroll
        for (int kk8 = 0; kk8 < 8; kk8 += 4) {
            const int co = ((kk8 + lq) ^ s) * 8;
            bf16x8 af[4], bfr[4];
#pragma unroll
            for (int mi = 0; mi < 4; ++mi)
                af[mi] = *(const bf16x8*)&As[(wr + mi * 16 + lrow) * 64 + co];
#pragma unroll
            for (int ni = 0; ni < 4; ++ni)
                bfr[ni] = *(const bf16x8*)&Bs[(wc + ni * 16 + lrow) * 64 + co];
#pragma unroll
            for (int mi = 0; mi < 4; ++mi)
#pragma unroll
                for (int ni = 0; ni < 4; ++ni)
                    acc[mi][ni] = MFMA16(af[mi], bfr[ni], acc[mi][ni]);
        }
    }
    const int rq = (l >> 4) * 4;
    float wv[4], bv[4];
#pragma unroll
    for (int ni = 0; ni < 4; ++ni) {
        const int col = n0 + wc + ni * 16 + lrow;
        wv[ni] = Wsv[col];
        bv[ni] = bias[col];
    }
#pragma unroll
    for (int mi = 0; mi < 4; ++mi) {
#pragma unroll
        for (int v = 0; v < 4; ++v) {
            float p = 0.0f;
#pragma unroll
            for (int ni = 0; ni < 4; ++ni)
                p += fmaxf(acc[mi][ni][v] + bv[ni], 0.0f) * wv[ni];
            p += __shfl_xor(p, 1, 64);
            p += __shfl_xor(p, 2, 64);
            p += __shfl_xor(p, 4, 64);
            p += __shfl_xor(p, 8, 64);
            if (lrow == 0)
                atomicAdd(&logit[r0 + m0 + wr + mi * 16 + rq + v], p);
        }
    }
}

// ---------------------------------------------------------------------------
// out[i,j] = out[j,i] = sigmoid(logit[r] + bs). One thread per tri-row.
// ---------------------------------------------------------------------------
__global__ __launch_bounds__(256)
void k_sig(const float* __restrict__ logit, const float* __restrict__ bsv,
           float* __restrict__ out)
{
    const int r = blockIdx.x * 256 + threadIdx.x;
    if (r >= TRI) return;
    int pi, pj; tri_decode(r, pi, pj);
    float v = 1.0f / (1.0f + __expf(-(logit[r] + bsv[0])));
    out[pi * NTRK + pj] = v;
    out[pj * NTRK + pi] = v;
}

// ---------------------------------------------------------------------------
extern "C" void kernel_launch(void* const* d_in, const int* in_sizes, int n_in,
                              void* d_out, int out_size, void* d_ws, size_t ws_size,
                              hipStream_t stream)
{
    const float* f   = (const float*)d_in[0];
    const float* Wc1 = (const float*)d_in[1];
    const float* bc1 = (const float*)d_in[2];
    const float* W1  = (const float*)d_in[3];
    const float* b1  = (const float*)d_in[4];
    const float* W2  = (const float*)d_in[5];
    const float* b2  = (const float*)d_in[6];
    const float* W3  = (const float*)d_in[7];
    const float* b3  = (const float*)d_in[8];
    const float* Wsv = (const float*)d_in[9];
    const float* bsv = (const float*)d_in[10];
    float* out = (float*)d_out;

    // ---- workspace layout ----
    // persistent: W1b 16M | W2b 4M | W3b 1M | fb 1.5M | g 3M | logit 75K
    // overlay region at chunkbase:
    //   phase A: Wc1b (32M) + camp (12M)   [dead before chunk loop]
    //   phase B: dist (8192R) + h1 (4096R); h2 (2048R) overlays dist.
    char* wsb = (char*)d_ws;
    size_t off = 0;
    u16*   W1b   = (u16*)(wsb + off);  off += (size_t)2048 * 4096 * 2;
    u16*   W2b   = (u16*)(wsb + off);  off += (size_t)1024 * 2048 * 2;
    u16*   W3b   = (u16*)(wsb + off);  off += (size_t)512  * 1024 * 2;
    u16*   fb    = (u16*)(wsb + off);  off += (size_t)192  * 4096 * 2;
    float* g     = (float*)(wsb + off); off += (size_t)192 * 4096 * 4;
    float* logit = (float*)(wsb + off); off += (size_t)TRIP * 4;
    const size_t chunkbase = off;
    u16*   Wc1b = (u16*)(wsb + chunkbase);
    float* camp = (float*)(wsb + chunkbase + (size_t)4096 * 4096 * 2);
    const size_t phaseA = (size_t)4096 * 4096 * 2 + (size_t)4 * 192 * 4096 * 4;

    // Chunk ladder (mult of 128). 12288 preferred over 14336: L1 grid becomes
    // 1536 blocks = 6.0 blocks/CU = 3x512 = 2x768 — tail-free under all
    // scheduling models; remainder 6400 rows in pass 2. (Round-9's 14336
    // split left 0.42- and 0.73-residency fractional rounds.)
    const int Rcand[6] = {18688, 12288, 9344, 4736, 2432, 1280};
    int R = 128;
    for (int c = 0; c < 6; ++c) {
        size_t chunk = (size_t)Rcand[c] * 12288;
        if (chunk < phaseA) chunk = phaseA;
        if (chunkbase + chunk <= ws_size) { R = Rcand[c]; break; }
    }
    u16* dist = (u16*)(wsb + chunkbase);
    u16* h1 = dist + (size_t)R * 4096;
    u16* h2 = dist;                       // overlays dist (dead after L1)

    hipMemsetAsync(logit, 0, (size_t)TRIP * 4, stream);
    k_cvt_all<<<(CVT_N + 255) / 256, 256, 0, stream>>>(
        Wc1, Wc1b, W1, W1b, W2, W2b, W3, W3b, f, fb);
    k_cam<<<dim3(3, 32, 4), 256, 0, stream>>>(fb, Wc1b, camp);
    k_gfin<<<768, 256, 0, stream>>>(camp, bc1, f, g);

    for (int r0 = 0; r0 < TRI; r0 += R) {
        int rows = TRIP - r0; if (rows > R) rows = R;   // mult of 128
        k_distgen<<<dim3(2, rows), 256, 0, stream>>>(g, dist, r0);
        k_gemm_relu<<<dim3(16, rows / 128), 256, 0, stream>>>(dist, W1b, b1, h1, 2048, 4096);
        k_gemm_relu<<<dim3(8,  rows / 128), 256, 0, stream>>>(h1, W2b, b2, h2, 1024, 2048);
        k_gemm3<<<dim3(4, rows / 128), 256, 0, stream>>>(h2, W3b, b3, Wsv, logit, r0);
    }
    k_sig<<<(TRI + 255) / 256, 256, 0, stream>>>(logit, bsv, out);
}